// Round 5
// baseline (1242.806 us; speedup 1.0000x reference)
//
#include <hip/hip_runtime.h>
#include <hip/hip_fp16.h>
#include <type_traits>

#define N_NODES 50000
#define IN_F    128
#define HID_F   128
#define OUT_F   64
#define E_EDGES 800000

#define RPB   128                                  // rows per bucket
#define NBUCK ((N_NODES + RPB - 1) / RPB)          // 391
#define BCAP  2560                                 // capacity (mean 2048, +11 sigma)
#define BIN_T   512
#define BIN_EPT 8
#define BIN_EPB (BIN_T * BIN_EPT)                  // 4096 edges per block
#define BIN_NB  ((E_EDGES + BIN_EPB - 1) / BIN_EPB)  // 196

__device__ __forceinline__ float relu_f(float x) { return x > 0.f ? x : 0.f; }

__device__ __forceinline__ void lds_addf(float* p, float v) {
    __hip_atomic_fetch_add(p, v, __ATOMIC_RELAXED, __HIP_MEMORY_SCOPE_WORKGROUP);
}

// ---------------- Dense GEMM: C[M,NF] = act(A)[M,K] @ W[K,NF], C in fp16 -----
template<int K, int NF, bool RELU_A, typename AT>
__global__ __launch_bounds__(256) void gemm64_kernel(const AT* __restrict__ A,
                                                     const float* __restrict__ W,
                                                     __half* __restrict__ C, int M) {
    __shared__ float As[16][68];
    __shared__ float Ws[16][68];
    const int tid = threadIdx.x;
    const int tx = tid & 15, ty = tid >> 4;
    const int row0 = blockIdx.y * 64;
    const int col0 = blockIdx.x * 64;
    float acc[4][4] = {};
    for (int k0 = 0; k0 < K; k0 += 16) {
        {
            const int r  = tid >> 2;
            const int kk = (tid & 3) << 2;
            const int grow = row0 + r;
            float a0 = 0.f, a1 = 0.f, a2 = 0.f, a3 = 0.f;
            if (grow < M) {
                if constexpr (std::is_same<AT, float>::value) {
                    float4 a = *(const float4*)(A + (long)grow * K + k0 + kk);
                    a0 = a.x; a1 = a.y; a2 = a.z; a3 = a.w;
                } else {
                    const __half2* p = (const __half2*)(A + (long)grow * K + k0 + kk);
                    float2 x0 = __half22float2(p[0]);
                    float2 x1 = __half22float2(p[1]);
                    a0 = x0.x; a1 = x0.y; a2 = x1.x; a3 = x1.y;
                }
            }
            if (RELU_A) { a0 = relu_f(a0); a1 = relu_f(a1); a2 = relu_f(a2); a3 = relu_f(a3); }
            As[kk + 0][r] = a0; As[kk + 1][r] = a1; As[kk + 2][r] = a2; As[kk + 3][r] = a3;
        }
        {
            const int kr = tid >> 4;
            const int c  = (tid & 15) << 2;
            float4 w = *(const float4*)(W + (long)(k0 + kr) * NF + col0 + c);
            *(float4*)&Ws[kr][c] = w;
        }
        __syncthreads();
#pragma unroll
        for (int kk = 0; kk < 16; ++kk) {
            float4 a = *(float4*)&As[kk][ty << 2];
            float4 w = *(float4*)&Ws[kk][tx << 2];
            acc[0][0] += a.x * w.x; acc[0][1] += a.x * w.y; acc[0][2] += a.x * w.z; acc[0][3] += a.x * w.w;
            acc[1][0] += a.y * w.x; acc[1][1] += a.y * w.y; acc[1][2] += a.y * w.z; acc[1][3] += a.y * w.w;
            acc[2][0] += a.z * w.x; acc[2][1] += a.z * w.y; acc[2][2] += a.z * w.z; acc[2][3] += a.z * w.w;
            acc[3][0] += a.w * w.x; acc[3][1] += a.w * w.y; acc[3][2] += a.w * w.z; acc[3][3] += a.w * w.w;
        }
        __syncthreads();
    }
#pragma unroll
    for (int i = 0; i < 4; ++i) {
        const int grow = row0 + (ty << 2) + i;
        if (grow < M) {
            union { __half2 h2[2]; uint2 u; } p;
            p.h2[0] = __floats2half2_rn(acc[i][0], acc[i][1]);
            p.h2[1] = __floats2half2_rn(acc[i][2], acc[i][3]);
            *(uint2*)(C + (long)grow * NF + col0 + (tx << 2)) = p.u;
        }
    }
}

__global__ void zero_int_kernel(int* __restrict__ p, int n) {
    int tid = blockIdx.x * blockDim.x + threadIdx.x;
    if (tid < n) p[tid] = 0;
}

// ---------------- Coalesced bucket binning ----------------
// Bucket b = row / RPB. Edge record: x = (row_local<<16)|col, y = val bits.
// Per-block LDS histogram -> one global atomicAdd per bucket -> contiguous runs.
__global__ __launch_bounds__(BIN_T) void bin_kernel(
        const int* __restrict__ row0, const int* __restrict__ col0, const float* __restrict__ val0,
        const int* __restrict__ row1, const int* __restrict__ col1, const float* __restrict__ val1,
        int* __restrict__ gfill, int2* __restrict__ bcv0, int2* __restrict__ bcv1) {
    const int g = blockIdx.y;
    const int*   rowi = g ? row1 : row0;
    const int*   coli = g ? col1 : col0;
    const float* vali = g ? val1 : val0;
    int*  gf  = gfill + g * NBUCK;
    int2* bcv = g ? bcv1 : bcv0;

    __shared__ int lhist[NBUCK];
    __shared__ int lbase[NBUCK];
    const int tid = threadIdx.x;
    for (int i = tid; i < NBUCK; i += BIN_T) lhist[i] = 0;
    __syncthreads();

    int rnk[BIN_EPT], bkt[BIN_EPT], cl[BIN_EPT], rw[BIN_EPT];
    float vl[BIN_EPT];
    const int e0 = blockIdx.x * BIN_EPB;
#pragma unroll
    for (int i = 0; i < BIN_EPT; ++i) {
        const int e = e0 + i * BIN_T + tid;
        bkt[i] = -1;
        if (e < E_EDGES) {
            const int r = rowi[e];
            rw[i] = r; cl[i] = coli[e]; vl[i] = vali[e];
            const int b = r / RPB;
            bkt[i] = b;
            rnk[i] = atomicAdd(&lhist[b], 1);
        }
    }
    __syncthreads();
    for (int i = tid; i < NBUCK; i += BIN_T) {
        const int c = lhist[i];
        lbase[i] = c ? atomicAdd(&gf[i], c) : 0;
    }
    __syncthreads();
#pragma unroll
    for (int i = 0; i < BIN_EPT; ++i) {
        if (bkt[i] >= 0) {
            const int pos = lbase[bkt[i]] + rnk[i];
            if (pos < BCAP)
                bcv[(long)bkt[i] * BCAP + pos] =
                    make_int2(((rw[i] & (RPB - 1)) << 16) | cl[i], __float_as_int(vl[i]));
        }
    }
}

// ---------------- Bucketed SpMM with LDS accumulators ----------------
// One block per bucket; acc[RPB][F] fp32 in LDS; edges applied via LDS atomics.
template<int F, bool OUT_HALF>
__global__ __launch_bounds__(512) void spmm_bucket_kernel(
        const int* __restrict__ gfill, const int2* __restrict__ bcv,
        const __half* __restrict__ sup, const float* __restrict__ bias,
        void* __restrict__ outv, int n) {
    __shared__ float acc[RPB * F];
    const int b = blockIdx.x;
    const int tid = threadIdx.x;
    const int lane = tid & 63, wv = tid >> 6;   // 8 waves
    for (int i = tid; i < RPB * F; i += 512) acc[i] = 0.f;
    __syncthreads();

    int cnt = gfill[b]; if (cnt > BCAP) cnt = BCAP;
    const int2* eb = bcv + (long)b * BCAP;

    for (int base = wv * 64; base < cnt; base += 8 * 64) {
        int m = cnt - base; if (m > 64) m = 64;
        int2 cv = make_int2(0, 0);
        if (lane < m) cv = eb[base + lane];
#pragma unroll 4
        for (int j = 0; j < m; ++j) {
            const int packed = __shfl(cv.x, j, 64);
            const float v = __int_as_float(__shfl(cv.y, j, 64));
            const int rl = packed >> 16;
            const int c  = packed & 0xFFFF;
            if constexpr (F == 128) {
                __half2 s = *((const __half2*)sup + (long)c * 64 + lane);
                float2 sf = __half22float2(s);
                lds_addf(&acc[rl * F + 2 * lane + 0], v * sf.x);
                lds_addf(&acc[rl * F + 2 * lane + 1], v * sf.y);
            } else {
                float sf = __half2float(sup[(long)c * F + lane]);
                lds_addf(&acc[rl * F + lane], v * sf);
            }
        }
    }
    __syncthreads();

    const int r0 = b * RPB;
    if constexpr (OUT_HALF) {
        __half2* o2 = (__half2*)outv;
        for (int i = tid; i < RPB * (F / 2); i += 512) {
            const int row = i / (F / 2), f2 = i % (F / 2);
            const int r = r0 + row;
            if (r < n) {
                const float v0 = acc[row * F + 2 * f2 + 0] + bias[2 * f2 + 0];
                const float v1 = acc[row * F + 2 * f2 + 1] + bias[2 * f2 + 1];
                o2[(long)r * (F / 2) + f2] = __floats2half2_rn(v0, v1);
            }
        }
    } else {
        float* o = (float*)outv;
        for (int i = tid; i < RPB * F; i += 512) {
            const int row = i / F, f = i % F;
            const int r = r0 + row;
            if (r < n) o[(long)r * F + f] = acc[row * F + f] + bias[f];
        }
    }
}

extern "C" void kernel_launch(void* const* d_in, const int* in_sizes, int n_in,
                              void* d_out, int out_size, void* d_ws, size_t ws_size,
                              hipStream_t stream) {
    const float* x    = (const float*)d_in[0];
    const int*   row0 = (const int*)d_in[1];
    const int*   col0 = (const int*)d_in[2];
    const float* val0 = (const float*)d_in[3];
    const int*   row1 = (const int*)d_in[4];
    const int*   col1 = (const int*)d_in[5];
    const float* val1 = (const float*)d_in[6];
    const float* W0   = (const float*)d_in[7];
    const float* b0   = (const float*)d_in[8];
    const float* W1   = (const float*)d_in[9];
    const float* b1   = (const float*)d_in[10];
    float* out = (float*)d_out;

    const int M = N_NODES;

    // Workspace layout (8B aligned):
    //   sup0: N*128 fp16 (12.8 MB)   -- reused as sup1 (N*64 fp16)
    //   h:    N*128 fp16 (12.8 MB)
    //   bcv0: NBUCK*BCAP int2 (8.0 MB)
    //   bcv1: NBUCK*BCAP int2 (8.0 MB)
    //   gfill: 2*NBUCK int
    __half* sup0 = (__half*)d_ws;
    __half* h    = sup0 + (long)N_NODES * HID_F;
    int2* bcv0   = (int2*)(h + (long)N_NODES * HID_F);
    int2* bcv1   = bcv0 + (long)NBUCK * BCAP;
    int*  gfill  = (int*)(bcv1 + (long)NBUCK * BCAP);
    __half* sup1 = sup0;  // sup0 dead after spmm0

    // ---- Binning (both graphs) ----
    zero_int_kernel<<<(2 * NBUCK + 255) / 256, 256, 0, stream>>>(gfill, 2 * NBUCK);
    bin_kernel<<<dim3(BIN_NB, 2), BIN_T, 0, stream>>>(row0, col0, val0, row1, col1, val1,
                                                      gfill, bcv0, bcv1);

    // ---- Layer 0 ----
    {
        dim3 grid(HID_F / 64, (M + 63) / 64);
        gemm64_kernel<IN_F, HID_F, false, float><<<grid, 256, 0, stream>>>(x, W0, sup0, M);
    }
    spmm_bucket_kernel<HID_F, true><<<NBUCK, 512, 0, stream>>>(gfill, bcv0, sup0, b0, h, N_NODES);

    // ---- Layer 1 ----
    {
        dim3 grid(OUT_F / 64, (M + 63) / 64);
        gemm64_kernel<HID_F, OUT_F, true, __half><<<grid, 256, 0, stream>>>(h, W1, sup1, M);
    }
    spmm_bucket_kernel<OUT_F, false><<<NBUCK, 512, 0, stream>>>(gfill + NBUCK, bcv1, sup1, b1,
                                                                out, N_NODES);
}

// Round 6
// 314.459 us; speedup vs baseline: 3.9522x; 3.9522x over previous
//
#include <hip/hip_runtime.h>
#include <hip/hip_fp16.h>
#include <type_traits>

#define N_NODES 50000
#define IN_F    128
#define HID_F   128
#define OUT_F   64
#define E_EDGES 800000

#define RPB   128                                  // rows per bucket
#define NBUCK ((N_NODES + RPB - 1) / RPB)          // 391
#define BCAP  2560                                 // capacity (mean 2048, +11 sigma)
#define BIN_T   512
#define BIN_EPT 8
#define BIN_EPB (BIN_T * BIN_EPT)                  // 4096 edges per block
#define BIN_NB  ((E_EDGES + BIN_EPB - 1) / BIN_EPB)  // 196

__device__ __forceinline__ float relu_f(float x) { return x > 0.f ? x : 0.f; }

// ---------------- Dense GEMM: C[M,NF] = act(A)[M,K] @ W[K,NF], C in fp16 -----
template<int K, int NF, bool RELU_A, typename AT>
__global__ __launch_bounds__(256) void gemm64_kernel(const AT* __restrict__ A,
                                                     const float* __restrict__ W,
                                                     __half* __restrict__ C, int M) {
    __shared__ float As[16][68];
    __shared__ float Ws[16][68];
    const int tid = threadIdx.x;
    const int tx = tid & 15, ty = tid >> 4;
    const int row0 = blockIdx.y * 64;
    const int col0 = blockIdx.x * 64;
    float acc[4][4] = {};
    for (int k0 = 0; k0 < K; k0 += 16) {
        {
            const int r  = tid >> 2;
            const int kk = (tid & 3) << 2;
            const int grow = row0 + r;
            float a0 = 0.f, a1 = 0.f, a2 = 0.f, a3 = 0.f;
            if (grow < M) {
                if constexpr (std::is_same<AT, float>::value) {
                    float4 a = *(const float4*)(A + (long)grow * K + k0 + kk);
                    a0 = a.x; a1 = a.y; a2 = a.z; a3 = a.w;
                } else {
                    const __half2* p = (const __half2*)(A + (long)grow * K + k0 + kk);
                    float2 x0 = __half22float2(p[0]);
                    float2 x1 = __half22float2(p[1]);
                    a0 = x0.x; a1 = x0.y; a2 = x1.x; a3 = x1.y;
                }
            }
            if (RELU_A) { a0 = relu_f(a0); a1 = relu_f(a1); a2 = relu_f(a2); a3 = relu_f(a3); }
            As[kk + 0][r] = a0; As[kk + 1][r] = a1; As[kk + 2][r] = a2; As[kk + 3][r] = a3;
        }
        {
            const int kr = tid >> 4;
            const int c  = (tid & 15) << 2;
            float4 w = *(const float4*)(W + (long)(k0 + kr) * NF + col0 + c);
            *(float4*)&Ws[kr][c] = w;
        }
        __syncthreads();
#pragma unroll
        for (int kk = 0; kk < 16; ++kk) {
            float4 a = *(float4*)&As[kk][ty << 2];
            float4 w = *(float4*)&Ws[kk][tx << 2];
            acc[0][0] += a.x * w.x; acc[0][1] += a.x * w.y; acc[0][2] += a.x * w.z; acc[0][3] += a.x * w.w;
            acc[1][0] += a.y * w.x; acc[1][1] += a.y * w.y; acc[1][2] += a.y * w.z; acc[1][3] += a.y * w.w;
            acc[2][0] += a.z * w.x; acc[2][1] += a.z * w.y; acc[2][2] += a.z * w.z; acc[2][3] += a.z * w.w;
            acc[3][0] += a.w * w.x; acc[3][1] += a.w * w.y; acc[3][2] += a.w * w.z; acc[3][3] += a.w * w.w;
        }
        __syncthreads();
    }
#pragma unroll
    for (int i = 0; i < 4; ++i) {
        const int grow = row0 + (ty << 2) + i;
        if (grow < M) {
            union { __half2 h2[2]; uint2 u; } p;
            p.h2[0] = __floats2half2_rn(acc[i][0], acc[i][1]);
            p.h2[1] = __floats2half2_rn(acc[i][2], acc[i][3]);
            *(uint2*)(C + (long)grow * NF + col0 + (tx << 2)) = p.u;
        }
    }
}

__global__ void zero_int_kernel(int* __restrict__ p, int n) {
    int tid = blockIdx.x * blockDim.x + threadIdx.x;
    if (tid < n) p[tid] = 0;
}

// ---------------- Coalesced bucket binning ----------------
// Bucket b = row / RPB. Edge record: x = (row_local<<16)|col, y = val bits.
__global__ __launch_bounds__(BIN_T) void bin_kernel(
        const int* __restrict__ row0, const int* __restrict__ col0, const float* __restrict__ val0,
        const int* __restrict__ row1, const int* __restrict__ col1, const float* __restrict__ val1,
        int* __restrict__ gfill, int2* __restrict__ bcv0, int2* __restrict__ bcv1) {
    const int g = blockIdx.y;
    const int*   rowi = g ? row1 : row0;
    const int*   coli = g ? col1 : col0;
    const float* vali = g ? val1 : val0;
    int*  gf  = gfill + g * NBUCK;
    int2* bcv = g ? bcv1 : bcv0;

    __shared__ int lhist[NBUCK];
    __shared__ int lbase[NBUCK];
    const int tid = threadIdx.x;
    for (int i = tid; i < NBUCK; i += BIN_T) lhist[i] = 0;
    __syncthreads();

    int rnk[BIN_EPT], bkt[BIN_EPT], cl[BIN_EPT], rw[BIN_EPT];
    float vl[BIN_EPT];
    const int e0 = blockIdx.x * BIN_EPB;
#pragma unroll
    for (int i = 0; i < BIN_EPT; ++i) {
        const int e = e0 + i * BIN_T + tid;
        bkt[i] = -1;
        if (e < E_EDGES) {
            const int r = rowi[e];
            rw[i] = r; cl[i] = coli[e]; vl[i] = vali[e];
            const int b = r / RPB;
            bkt[i] = b;
            rnk[i] = atomicAdd(&lhist[b], 1);
        }
    }
    __syncthreads();
    for (int i = tid; i < NBUCK; i += BIN_T) {
        const int c = lhist[i];
        lbase[i] = c ? atomicAdd(&gf[i], c) : 0;
    }
    __syncthreads();
#pragma unroll
    for (int i = 0; i < BIN_EPT; ++i) {
        if (bkt[i] >= 0) {
            const int pos = lbase[bkt[i]] + rnk[i];
            if (pos < BCAP)
                bcv[(long)bkt[i] * BCAP + pos] =
                    make_int2(((rw[i] & (RPB - 1)) << 16) | cl[i], __float_as_int(vl[i]));
        }
    }
}

// ---------------- Per-bucket counting sort (in place) + rowstarts ----------
// One block per (bucket, graph). Histogram by row_local, LDS prefix, scatter
// into LDS, coalesced write-back, bucket-local rowstart[RPB+1].
__global__ __launch_bounds__(256) void sort_kernel(const int* __restrict__ gfill,
                                                   int2* __restrict__ bcv0,
                                                   int2* __restrict__ bcv1,
                                                   int* __restrict__ rs0,
                                                   int* __restrict__ rs1) {
    const int g = blockIdx.y;
    const int b = blockIdx.x;
    int2* buf = (g ? bcv1 : bcv0) + (long)b * BCAP;
    int*  rs  = (g ? rs1 : rs0) + b * (RPB + 1);

    __shared__ int2 sbuf[BCAP];       // 20 KB
    __shared__ int  cur[RPB];         // histogram, then cursor
    __shared__ int  sc[RPB];          // scan scratch
    __shared__ int  start[RPB + 1];

    const int tid = threadIdx.x;
    int cnt = gfill[g * NBUCK + b];
    if (cnt > BCAP) cnt = BCAP;

    if (tid < RPB) cur[tid] = 0;
    __syncthreads();
    // pass 1: histogram of row_local
    for (int e = tid; e < cnt; e += 256)
        atomicAdd(&cur[buf[e].x >> 16], 1);
    __syncthreads();
    // inclusive scan over 128 counters (guarded Hillis-Steele)
    if (tid < RPB) sc[tid] = cur[tid];
    __syncthreads();
    for (int off = 1; off < RPB; off <<= 1) {
        int v = 0;
        if (tid < RPB && tid >= off) v = sc[tid - off];
        __syncthreads();
        if (tid < RPB) sc[tid] += v;
        __syncthreads();
    }
    if (tid < RPB) {
        start[tid + 1] = sc[tid];
        if (tid == 0) start[0] = 0;
        cur[tid] = (tid == 0) ? 0 : sc[tid - 1];  // cursor = exclusive start
    }
    __syncthreads();
    // pass 2: scatter into LDS sorted buffer
    for (int e = tid; e < cnt; e += 256) {
        int2 r = buf[e];
        int pos = atomicAdd(&cur[r.x >> 16], 1);
        sbuf[pos] = r;
    }
    __syncthreads();
    // coalesced write-back (in place) + rowstarts
    for (int e = tid; e < cnt; e += 256) buf[e] = sbuf[e];
    for (int i = tid; i <= RPB; i += 256) rs[i] = start[i];
}

// ---------------- SpMM: wave per row over sorted bucket edges --------------
// out[r] = bias + sum val * sup[col]; sup fp16, fp32 accumulate. F = 64*VEC.
template<int F, int VEC, bool OUT_HALF>
__global__ __launch_bounds__(256) void spmm_kernel(const int* __restrict__ rs,
                                                   const int2* __restrict__ bcv,
                                                   const __half* __restrict__ sup,
                                                   const float* __restrict__ bias,
                                                   void* __restrict__ outv, int n) {
    static_assert(F == 64 * VEC, "one wave per row");
    const int wave = threadIdx.x >> 6;
    const int lane = threadIdx.x & 63;
    const int r = blockIdx.x * 4 + wave;
    if (r >= n) return;
    const int b  = r >> 7;          // r / RPB
    const int rl = r & (RPB - 1);
    const int* rsb = rs + b * (RPB + 1);
    const int start = rsb[rl];
    const int end   = rsb[rl + 1];
    const int2* eb = bcv + (long)b * BCAP;
    const int f0 = lane * VEC;
    float acc0 = bias[f0];
    float acc1 = (VEC == 2) ? bias[f0 + 1] : 0.f;
    for (int e = start; e < end; ++e) {
        const int2 cv = eb[e];
        const int c   = cv.x & 0xFFFF;
        const float v = __int_as_float(cv.y);
        if constexpr (VEC == 2) {
            __half2 s = *(const __half2*)(sup + (long)c * F + f0);
            float2 sf = __half22float2(s);
            acc0 += v * sf.x;
            acc1 += v * sf.y;
        } else {
            acc0 += v * __half2float(sup[(long)c * F + f0]);
        }
    }
    if constexpr (OUT_HALF) {
        __half* out = (__half*)outv;
        *(__half2*)(out + (long)r * F + f0) = __floats2half2_rn(acc0, acc1);
    } else {
        float* out = (float*)outv;
        out[(long)r * F + f0] = acc0;
    }
}

extern "C" void kernel_launch(void* const* d_in, const int* in_sizes, int n_in,
                              void* d_out, int out_size, void* d_ws, size_t ws_size,
                              hipStream_t stream) {
    const float* x    = (const float*)d_in[0];
    const int*   row0 = (const int*)d_in[1];
    const int*   col0 = (const int*)d_in[2];
    const float* val0 = (const float*)d_in[3];
    const int*   row1 = (const int*)d_in[4];
    const int*   col1 = (const int*)d_in[5];
    const float* val1 = (const float*)d_in[6];
    const float* W0   = (const float*)d_in[7];
    const float* b0   = (const float*)d_in[8];
    const float* W1   = (const float*)d_in[9];
    const float* b1   = (const float*)d_in[10];
    float* out = (float*)d_out;

    const int M = N_NODES;

    // Workspace layout (8B aligned):
    //   sup0: N*128 fp16 (12.8 MB)   -- reused as sup1 (N*64 fp16)
    //   h:    N*128 fp16 (12.8 MB)
    //   bcv0, bcv1: NBUCK*BCAP int2 (8.0 MB each), sorted in place
    //   rs0, rs1: NBUCK*(RPB+1) int (~0.2 MB each)
    //   gfill: 2*NBUCK int
    __half* sup0 = (__half*)d_ws;
    __half* h    = sup0 + (long)N_NODES * HID_F;
    int2* bcv0   = (int2*)(h + (long)N_NODES * HID_F);
    int2* bcv1   = bcv0 + (long)NBUCK * BCAP;
    int*  rs0    = (int*)(bcv1 + (long)NBUCK * BCAP);
    int*  rs1    = rs0 + NBUCK * (RPB + 1);
    int*  gfill  = rs1 + NBUCK * (RPB + 1);
    __half* sup1 = sup0;  // sup0 dead after spmm0

    const int SPMM_B = (N_NODES + 3) / 4;

    // ---- Build sorted buckets for both graphs ----
    zero_int_kernel<<<(2 * NBUCK + 255) / 256, 256, 0, stream>>>(gfill, 2 * NBUCK);
    bin_kernel<<<dim3(BIN_NB, 2), BIN_T, 0, stream>>>(row0, col0, val0, row1, col1, val1,
                                                      gfill, bcv0, bcv1);
    sort_kernel<<<dim3(NBUCK, 2), 256, 0, stream>>>(gfill, bcv0, bcv1, rs0, rs1);

    // ---- Layer 0 ----
    {
        dim3 grid(HID_F / 64, (M + 63) / 64);
        gemm64_kernel<IN_F, HID_F, false, float><<<grid, 256, 0, stream>>>(x, W0, sup0, M);
    }
    spmm_kernel<HID_F, 2, true><<<SPMM_B, 256, 0, stream>>>(rs0, bcv0, sup0, b0, h, N_NODES);

    // ---- Layer 1 ----
    {
        dim3 grid(OUT_F / 64, (M + 63) / 64);
        gemm64_kernel<HID_F, OUT_F, true, __half><<<grid, 256, 0, stream>>>(h, W1, sup1, M);
    }
    spmm_kernel<OUT_F, 1, false><<<SPMM_B, 256, 0, stream>>>(rs1, bcv1, sup1, b1, out, N_NODES);
}

// Round 7
// 204.197 us; speedup vs baseline: 6.0863x; 1.5400x over previous
//
#include <hip/hip_runtime.h>
#include <hip/hip_fp16.h>

#define N_NODES 50000
#define IN_F    128
#define HID_F   128
#define OUT_F   64
#define E_EDGES 800000

#define RPB   128                                  // rows per bucket
#define NBUCK ((N_NODES + RPB - 1) / RPB)          // 391
#define BCAP  2560                                 // capacity (mean 2048, +11 sigma)
#define BIN_T   512
#define BIN_EPT 8
#define BIN_EPB (BIN_T * BIN_EPT)                  // 4096 edges per block
#define BIN_NB  ((E_EDGES + BIN_EPB - 1) / BIN_EPB)  // 196

typedef _Float16 half8 __attribute__((ext_vector_type(8)));
typedef float    floatx4 __attribute__((ext_vector_type(4)));

// ---------------- fp32 -> fp16 converts ----------------
__global__ void convert_x_kernel(const float* __restrict__ x, __half* __restrict__ y, int n4) {
    int i = blockIdx.x * 256 + threadIdx.x;
    if (i < n4) {
        float4 v = ((const float4*)x)[i];
        ((__half2*)y)[2 * i + 0] = __floats2half2_rn(v.x, v.y);
        ((__half2*)y)[2 * i + 1] = __floats2half2_rn(v.z, v.w);
    }
}

// W0[k][n] (128x128) -> wt0[n][k] fp16 ; W1[k][n] (128x64) -> wt1[n][k] fp16
__global__ void convert_w_kernel(const float* __restrict__ W0, const float* __restrict__ W1,
                                 __half* __restrict__ wt0, __half* __restrict__ wt1) {
    int tid = blockIdx.x * 256 + threadIdx.x;
    if (blockIdx.y == 0) {
        if (tid < IN_F * HID_F) {
            int k = tid >> 7, n = tid & 127;
            wt0[n * IN_F + k] = __float2half(W0[tid]);
        }
    } else {
        if (tid < HID_F * OUT_F) {
            int k = tid / OUT_F, n = tid % OUT_F;
            wt1[n * HID_F + k] = __float2half(W1[tid]);
        }
    }
}

// ---------------- MFMA GEMM: C[M,NF] = act(A)[M,K] @ W[K,NF], all fp16 io ----
// Wt is W transposed [NF][K] fp16. Block = 4 waves, 64 rows; wave w -> rows
// base+16w..+15, full NF via NT col-tiles. 16x16x32 f16 MFMA, fp32 acc.
// Layouts (m89/m120-verified): A/B frag k = quad*8+j, C/D col=lane&15,
// row=quad*4+reg.
template<int K, int NF, bool RELU_A>
__global__ __launch_bounds__(256) void gemm_mfma_kernel(const __half* __restrict__ A,
                                                        const __half* __restrict__ Wt,
                                                        __half* __restrict__ C, int M) {
    constexpr int KP = K + 8;          // LDS stride in halves: +16B => 2-way bank alias (free)
    constexpr int NT = NF / 16;
    __shared__ _Float16 Ws[NF * KP];
    const int tid = threadIdx.x;
    constexpr int CH = NF * K / 8;
    for (int c = tid; c < CH; c += 256) {
        const int n = c / (K / 8), ko = (c % (K / 8)) * 8;
        *(half8*)&Ws[n * KP + ko] = *(const half8*)(Wt + n * K + ko);
    }
    __syncthreads();

    const int wv = tid >> 6, lane = tid & 63;
    const int quad = lane >> 4, l16 = lane & 15;
    const int rowb = blockIdx.x * 64 + wv * 16;
    const int arow = rowb + l16;

    floatx4 acc[NT] = {};
#pragma unroll
    for (int ks = 0; ks < K; ks += 32) {
        half8 af = {};
        if (arow < M) af = *(const half8*)(A + (long)arow * K + ks + quad * 8);
        if (RELU_A) {
            _Float16 z = (_Float16)0;
#pragma unroll
            for (int j = 0; j < 8; ++j) af[j] = af[j] > z ? af[j] : z;
        }
#pragma unroll
        for (int t = 0; t < NT; ++t) {
            half8 bf = *(const half8*)&Ws[(t * 16 + l16) * KP + ks + quad * 8];
            acc[t] = __builtin_amdgcn_mfma_f32_16x16x32_f16(af, bf, acc[t], 0, 0, 0);
        }
    }
#pragma unroll
    for (int t = 0; t < NT; ++t) {
        const int col = t * 16 + l16;
#pragma unroll
        for (int i = 0; i < 4; ++i) {
            const int row = rowb + quad * 4 + i;
            if (row < M) C[(long)row * NF + col] = __float2half(acc[t][i]);
        }
    }
}

__global__ void zero_int_kernel(int* __restrict__ p, int n) {
    int tid = blockIdx.x * blockDim.x + threadIdx.x;
    if (tid < n) p[tid] = 0;
}

// ---------------- Coalesced bucket binning ----------------
__global__ __launch_bounds__(BIN_T) void bin_kernel(
        const int* __restrict__ row0, const int* __restrict__ col0, const float* __restrict__ val0,
        const int* __restrict__ row1, const int* __restrict__ col1, const float* __restrict__ val1,
        int* __restrict__ gfill, int2* __restrict__ bcv0, int2* __restrict__ bcv1) {
    const int g = blockIdx.y;
    const int*   rowi = g ? row1 : row0;
    const int*   coli = g ? col1 : col0;
    const float* vali = g ? val1 : val0;
    int*  gf  = gfill + g * NBUCK;
    int2* bcv = g ? bcv1 : bcv0;

    __shared__ int lhist[NBUCK];
    __shared__ int lbase[NBUCK];
    const int tid = threadIdx.x;
    for (int i = tid; i < NBUCK; i += BIN_T) lhist[i] = 0;
    __syncthreads();

    int rnk[BIN_EPT], bkt[BIN_EPT], cl[BIN_EPT], rw[BIN_EPT];
    float vl[BIN_EPT];
    const int e0 = blockIdx.x * BIN_EPB;
#pragma unroll
    for (int i = 0; i < BIN_EPT; ++i) {
        const int e = e0 + i * BIN_T + tid;
        bkt[i] = -1;
        if (e < E_EDGES) {
            const int r = rowi[e];
            rw[i] = r; cl[i] = coli[e]; vl[i] = vali[e];
            const int b = r / RPB;
            bkt[i] = b;
            rnk[i] = atomicAdd(&lhist[b], 1);
        }
    }
    __syncthreads();
    for (int i = tid; i < NBUCK; i += BIN_T) {
        const int c = lhist[i];
        lbase[i] = c ? atomicAdd(&gf[i], c) : 0;
    }
    __syncthreads();
#pragma unroll
    for (int i = 0; i < BIN_EPT; ++i) {
        if (bkt[i] >= 0) {
            const int pos = lbase[bkt[i]] + rnk[i];
            if (pos < BCAP)
                bcv[(long)bkt[i] * BCAP + pos] =
                    make_int2(((rw[i] & (RPB - 1)) << 16) | cl[i], __float_as_int(vl[i]));
        }
    }
}

// ---------------- Per-bucket counting sort (in place) + rowstarts ----------
__global__ __launch_bounds__(256) void sort_kernel(const int* __restrict__ gfill,
                                                   int2* __restrict__ bcv0,
                                                   int2* __restrict__ bcv1,
                                                   int* __restrict__ rs0,
                                                   int* __restrict__ rs1) {
    const int g = blockIdx.y;
    const int b = blockIdx.x;
    int2* buf = (g ? bcv1 : bcv0) + (long)b * BCAP;
    int*  rs  = (g ? rs1 : rs0) + b * (RPB + 1);

    __shared__ int2 sbuf[BCAP];
    __shared__ int  cur[RPB];
    __shared__ int  sc[RPB];
    __shared__ int  start[RPB + 1];

    const int tid = threadIdx.x;
    int cnt = gfill[g * NBUCK + b];
    if (cnt > BCAP) cnt = BCAP;

    if (tid < RPB) cur[tid] = 0;
    __syncthreads();
    for (int e = tid; e < cnt; e += 256)
        atomicAdd(&cur[buf[e].x >> 16], 1);
    __syncthreads();
    if (tid < RPB) sc[tid] = cur[tid];
    __syncthreads();
    for (int off = 1; off < RPB; off <<= 1) {
        int v = 0;
        if (tid < RPB && tid >= off) v = sc[tid - off];
        __syncthreads();
        if (tid < RPB) sc[tid] += v;
        __syncthreads();
    }
    if (tid < RPB) {
        start[tid + 1] = sc[tid];
        if (tid == 0) start[0] = 0;
        cur[tid] = (tid == 0) ? 0 : sc[tid - 1];
    }
    __syncthreads();
    for (int e = tid; e < cnt; e += 256) {
        int2 r = buf[e];
        int pos = atomicAdd(&cur[r.x >> 16], 1);
        sbuf[pos] = r;
    }
    __syncthreads();
    for (int e = tid; e < cnt; e += 256) buf[e] = sbuf[e];
    for (int i = tid; i <= RPB; i += 256) rs[i] = start[i];
}

// ---------------- SpMM: wave per row, 4-deep gather pipelining -------------
// Lanes cooperatively load up to 64 edge records (coalesced), __shfl
// broadcast, 4 independent gathers per batch for MLP. F = 64*VEC.
template<int F, int VEC, bool OUT_HALF>
__global__ __launch_bounds__(256) void spmm_kernel(const int* __restrict__ rs,
                                                   const int2* __restrict__ bcv,
                                                   const __half* __restrict__ sup,
                                                   const float* __restrict__ bias,
                                                   void* __restrict__ outv, int n) {
    static_assert(F == 64 * VEC, "one wave per row");
    const int wave = threadIdx.x >> 6;
    const int lane = threadIdx.x & 63;
    const int r = blockIdx.x * 4 + wave;
    if (r >= n) return;
    const int b  = r >> 7;
    const int rl = r & (RPB - 1);
    const int* rsb = rs + b * (RPB + 1);
    const int start = rsb[rl];
    const int end   = rsb[rl + 1];
    const int2* eb = bcv + (long)b * BCAP;
    const int f0 = lane * VEC;
    float acc0 = bias[f0];
    float acc1 = (VEC == 2) ? bias[f0 + 1] : 0.f;

    for (int base = start; base < end; base += 64) {
        const int m = min(64, end - base);
        int2 cvl = make_int2(0, 0);
        if (lane < m) cvl = eb[base + lane];
        int j = 0;
        for (; j + 4 <= m; j += 4) {
            const int   p0 = __shfl(cvl.x, j + 0, 64);
            const float v0 = __int_as_float(__shfl(cvl.y, j + 0, 64));
            const int   p1 = __shfl(cvl.x, j + 1, 64);
            const float v1 = __int_as_float(__shfl(cvl.y, j + 1, 64));
            const int   p2 = __shfl(cvl.x, j + 2, 64);
            const float v2 = __int_as_float(__shfl(cvl.y, j + 2, 64));
            const int   p3 = __shfl(cvl.x, j + 3, 64);
            const float v3 = __int_as_float(__shfl(cvl.y, j + 3, 64));
            if constexpr (VEC == 2) {
                __half2 s0 = *(const __half2*)(sup + (long)(p0 & 0xFFFF) * F + f0);
                __half2 s1 = *(const __half2*)(sup + (long)(p1 & 0xFFFF) * F + f0);
                __half2 s2 = *(const __half2*)(sup + (long)(p2 & 0xFFFF) * F + f0);
                __half2 s3 = *(const __half2*)(sup + (long)(p3 & 0xFFFF) * F + f0);
                float2 g0 = __half22float2(s0), g1 = __half22float2(s1);
                float2 g2 = __half22float2(s2), g3 = __half22float2(s3);
                acc0 += v0 * g0.x; acc1 += v0 * g0.y;
                acc0 += v1 * g1.x; acc1 += v1 * g1.y;
                acc0 += v2 * g2.x; acc1 += v2 * g2.y;
                acc0 += v3 * g3.x; acc1 += v3 * g3.y;
            } else {
                float s0 = __half2float(sup[(long)(p0 & 0xFFFF) * F + f0]);
                float s1 = __half2float(sup[(long)(p1 & 0xFFFF) * F + f0]);
                float s2 = __half2float(sup[(long)(p2 & 0xFFFF) * F + f0]);
                float s3 = __half2float(sup[(long)(p3 & 0xFFFF) * F + f0]);
                acc0 += v0 * s0 + v1 * s1 + v2 * s2 + v3 * s3;
            }
        }
        for (; j < m; ++j) {
            const int   p = __shfl(cvl.x, j, 64);
            const float v = __int_as_float(__shfl(cvl.y, j, 64));
            if constexpr (VEC == 2) {
                float2 g = __half22float2(*(const __half2*)(sup + (long)(p & 0xFFFF) * F + f0));
                acc0 += v * g.x; acc1 += v * g.y;
            } else {
                acc0 += v * __half2float(sup[(long)(p & 0xFFFF) * F + f0]);
            }
        }
    }
    if constexpr (OUT_HALF) {
        __half* out = (__half*)outv;
        *(__half2*)(out + (long)r * F + f0) = __floats2half2_rn(acc0, acc1);
    } else {
        float* out = (float*)outv;
        out[(long)r * F + f0] = acc0;
    }
}

extern "C" void kernel_launch(void* const* d_in, const int* in_sizes, int n_in,
                              void* d_out, int out_size, void* d_ws, size_t ws_size,
                              hipStream_t stream) {
    const float* x    = (const float*)d_in[0];
    const int*   row0 = (const int*)d_in[1];
    const int*   col0 = (const int*)d_in[2];
    const float* val0 = (const float*)d_in[3];
    const int*   row1 = (const int*)d_in[4];
    const int*   col1 = (const int*)d_in[5];
    const float* val1 = (const float*)d_in[6];
    const float* W0   = (const float*)d_in[7];
    const float* b0   = (const float*)d_in[8];
    const float* W1   = (const float*)d_in[9];
    const float* b1   = (const float*)d_in[10];
    float* out = (float*)d_out;

    const int M = N_NODES;

    // Workspace layout (8B aligned):
    //   x16:  N*128 fp16 (12.8 MB)
    //   sup0: N*128 fp16 (12.8 MB) -- reused as sup1
    //   h:    N*128 fp16 (12.8 MB)
    //   bcv0, bcv1: NBUCK*BCAP int2 (8 MB each)
    //   rs0, rs1, gfill, wt0, wt1
    __half* x16  = (__half*)d_ws;
    __half* sup0 = x16 + (long)N_NODES * IN_F;
    __half* h    = sup0 + (long)N_NODES * HID_F;
    int2* bcv0   = (int2*)(h + (long)N_NODES * HID_F);
    int2* bcv1   = bcv0 + (long)NBUCK * BCAP;
    int*  rs0    = (int*)(bcv1 + (long)NBUCK * BCAP);
    int*  rs1    = rs0 + NBUCK * (RPB + 1);
    int*  gfill  = rs1 + NBUCK * (RPB + 1);
    __half* wt0  = (__half*)(gfill + 2 * NBUCK + 2);  // [HID_F][IN_F]
    __half* wt1  = wt0 + IN_F * HID_F;                 // [OUT_F][HID_F]
    __half* sup1 = sup0;

    const int SPMM_B = (N_NODES + 3) / 4;

    // ---- Converts + sorted-bucket build ----
    zero_int_kernel<<<(2 * NBUCK + 255) / 256, 256, 0, stream>>>(gfill, 2 * NBUCK);
    convert_x_kernel<<<(N_NODES * IN_F / 4 + 255) / 256, 256, 0, stream>>>(x, x16, N_NODES * IN_F / 4);
    convert_w_kernel<<<dim3(64, 2), 256, 0, stream>>>(W0, W1, wt0, wt1);
    bin_kernel<<<dim3(BIN_NB, 2), BIN_T, 0, stream>>>(row0, col0, val0, row1, col1, val1,
                                                      gfill, bcv0, bcv1);
    sort_kernel<<<dim3(NBUCK, 2), 256, 0, stream>>>(gfill, bcv0, bcv1, rs0, rs1);

    // ---- Layer 0 ----
    gemm_mfma_kernel<IN_F, HID_F, false><<<(M + 63) / 64, 256, 0, stream>>>(x16, wt0, sup0, M);
    spmm_kernel<HID_F, 2, true><<<SPMM_B, 256, 0, stream>>>(rs0, bcv0, sup0, b0, h, N_NODES);

    // ---- Layer 1 ----
    gemm_mfma_kernel<HID_F, OUT_F, true><<<(M + 63) / 64, 256, 0, stream>>>(h, wt1, sup1, M);
    spmm_kernel<OUT_F, 1, false><<<SPMM_B, 256, 0, stream>>>(rs1, bcv1, sup1, b1, out, N_NODES);
}

// Round 8
// 198.270 us; speedup vs baseline: 6.2682x; 1.0299x over previous
//
#include <hip/hip_runtime.h>
#include <hip/hip_fp16.h>
#include <type_traits>

#define N_NODES 50000
#define IN_F    128
#define HID_F   128
#define OUT_F   64
#define E_EDGES 800000

#define RPB   128                                  // rows per bucket
#define NBUCK ((N_NODES + RPB - 1) / RPB)          // 391
#define BCAP  2560                                 // capacity (mean 2048, +11 sigma)
#define BIN_T   512
#define BIN_EPT 8
#define BIN_EPB (BIN_T * BIN_EPT)                  // 4096 edges per block
#define BIN_NB  ((E_EDGES + BIN_EPB - 1) / BIN_EPB)  // 196

typedef _Float16 half8 __attribute__((ext_vector_type(8)));
typedef float    floatx4 __attribute__((ext_vector_type(4)));

// ---------------- Prep: zero gfill + convert W0/W1 to fp16 transposed -------
__global__ __launch_bounds__(256) void prep_kernel(const float* __restrict__ W0,
                                                   const float* __restrict__ W1,
                                                   __half* __restrict__ wt0,
                                                   __half* __restrict__ wt1,
                                                   int* __restrict__ gfill) {
    int tid = blockIdx.x * 256 + threadIdx.x;
    if (tid < IN_F * HID_F) {               // wt0[n][k] = W0[k][n], 128x128
        int k = tid >> 7, n = tid & 127;
        wt0[n * IN_F + k] = __float2half(W0[tid]);
    }
    if (tid < HID_F * OUT_F) {              // wt1[n][k] = W1[k][n], 128x64
        int k = tid / OUT_F, n = tid % OUT_F;
        wt1[n * HID_F + k] = __float2half(W1[tid]);
    }
    if (tid < 2 * NBUCK) gfill[tid] = 0;
}

// ---------------- MFMA GEMM: C[M,NF] = act(A)[M,K] @ W[K,NF] ----------------
// A fp32 or fp16; Wt = W^T [NF][K] fp16 staged in LDS. 4 waves, 64 rows/block,
// 16x16x32 f16 MFMA, fp32 acc. Layouts m89/m120-verified.
template<int K, int NF, bool RELU_A, typename AT>
__global__ __launch_bounds__(256) void gemm_mfma_kernel(const AT* __restrict__ A,
                                                        const __half* __restrict__ Wt,
                                                        __half* __restrict__ C, int M) {
    constexpr int KP = K + 8;          // +16B stride: 2-way bank alias (free)
    constexpr int NT = NF / 16;
    __shared__ _Float16 Ws[NF * KP];
    const int tid = threadIdx.x;
    constexpr int CH = NF * K / 8;
    for (int c = tid; c < CH; c += 256) {
        const int n = c / (K / 8), ko = (c % (K / 8)) * 8;
        *(half8*)&Ws[n * KP + ko] = *(const half8*)(Wt + n * K + ko);
    }
    __syncthreads();

    const int wv = tid >> 6, lane = tid & 63;
    const int quad = lane >> 4, l16 = lane & 15;
    const int rowb = blockIdx.x * 64 + wv * 16;
    const int arow = rowb + l16;

    floatx4 acc[NT] = {};
#pragma unroll
    for (int ks = 0; ks < K; ks += 32) {
        half8 af = {};
        if (arow < M) {
            if constexpr (std::is_same<AT, float>::value) {
                const float4* p = (const float4*)(A + (long)arow * K + ks + quad * 8);
                float4 u = p[0], w = p[1];
                af[0] = (_Float16)u.x; af[1] = (_Float16)u.y;
                af[2] = (_Float16)u.z; af[3] = (_Float16)u.w;
                af[4] = (_Float16)w.x; af[5] = (_Float16)w.y;
                af[6] = (_Float16)w.z; af[7] = (_Float16)w.w;
            } else {
                af = *(const half8*)(A + (long)arow * K + ks + quad * 8);
            }
        }
        if (RELU_A) {
            _Float16 z = (_Float16)0;
#pragma unroll
            for (int j = 0; j < 8; ++j) af[j] = af[j] > z ? af[j] : z;
        }
#pragma unroll
        for (int t = 0; t < NT; ++t) {
            half8 bf = *(const half8*)&Ws[(t * 16 + l16) * KP + ks + quad * 8];
            acc[t] = __builtin_amdgcn_mfma_f32_16x16x32_f16(af, bf, acc[t], 0, 0, 0);
        }
    }
#pragma unroll
    for (int t = 0; t < NT; ++t) {
        const int col = t * 16 + l16;
#pragma unroll
        for (int i = 0; i < 4; ++i) {
            const int row = rowb + quad * 4 + i;
            if (row < M) C[(long)row * NF + col] = __float2half(acc[t][i]);
        }
    }
}

// ---------------- Coalesced bucket binning ----------------
__global__ __launch_bounds__(BIN_T) void bin_kernel(
        const int* __restrict__ row0, const int* __restrict__ col0, const float* __restrict__ val0,
        const int* __restrict__ row1, const int* __restrict__ col1, const float* __restrict__ val1,
        int* __restrict__ gfill, int2* __restrict__ bcv0, int2* __restrict__ bcv1) {
    const int g = blockIdx.y;
    const int*   rowi = g ? row1 : row0;
    const int*   coli = g ? col1 : col0;
    const float* vali = g ? val1 : val0;
    int*  gf  = gfill + g * NBUCK;
    int2* bcv = g ? bcv1 : bcv0;

    __shared__ int lhist[NBUCK];
    __shared__ int lbase[NBUCK];
    const int tid = threadIdx.x;
    for (int i = tid; i < NBUCK; i += BIN_T) lhist[i] = 0;
    __syncthreads();

    int rnk[BIN_EPT], bkt[BIN_EPT], cl[BIN_EPT], rw[BIN_EPT];
    float vl[BIN_EPT];
    const int e0 = blockIdx.x * BIN_EPB;
#pragma unroll
    for (int i = 0; i < BIN_EPT; ++i) {
        const int e = e0 + i * BIN_T + tid;
        bkt[i] = -1;
        if (e < E_EDGES) {
            const int r = rowi[e];
            rw[i] = r; cl[i] = coli[e]; vl[i] = vali[e];
            const int b = r / RPB;
            bkt[i] = b;
            rnk[i] = atomicAdd(&lhist[b], 1);
        }
    }
    __syncthreads();
    for (int i = tid; i < NBUCK; i += BIN_T) {
        const int c = lhist[i];
        lbase[i] = c ? atomicAdd(&gf[i], c) : 0;
    }
    __syncthreads();
#pragma unroll
    for (int i = 0; i < BIN_EPT; ++i) {
        if (bkt[i] >= 0) {
            const int pos = lbase[bkt[i]] + rnk[i];
            if (pos < BCAP)
                bcv[(long)bkt[i] * BCAP + pos] =
                    make_int2(((rw[i] & (RPB - 1)) << 16) | cl[i], __float_as_int(vl[i]));
        }
    }
}

// ---------------- Per-bucket counting sort (in place) + rowstarts ----------
#define SORT_T 512
__global__ __launch_bounds__(SORT_T) void sort_kernel(const int* __restrict__ gfill,
                                                      int2* __restrict__ bcv0,
                                                      int2* __restrict__ bcv1,
                                                      int* __restrict__ rs0,
                                                      int* __restrict__ rs1) {
    const int g = blockIdx.y;
    const int b = blockIdx.x;
    int2* buf = (g ? bcv1 : bcv0) + (long)b * BCAP;
    int*  rs  = (g ? rs1 : rs0) + b * (RPB + 1);

    __shared__ int2 sbuf[BCAP];
    __shared__ int  cur[RPB];
    __shared__ int  sc[RPB];
    __shared__ int  start[RPB + 1];

    const int tid = threadIdx.x;
    int cnt = gfill[g * NBUCK + b];
    if (cnt > BCAP) cnt = BCAP;

    if (tid < RPB) cur[tid] = 0;
    __syncthreads();
    for (int e = tid; e < cnt; e += SORT_T)
        atomicAdd(&cur[buf[e].x >> 16], 1);
    __syncthreads();
    if (tid < RPB) sc[tid] = cur[tid];
    __syncthreads();
    for (int off = 1; off < RPB; off <<= 1) {
        int v = 0;
        if (tid < RPB && tid >= off) v = sc[tid - off];
        __syncthreads();
        if (tid < RPB) sc[tid] += v;
        __syncthreads();
    }
    if (tid < RPB) {
        start[tid + 1] = sc[tid];
        if (tid == 0) start[0] = 0;
        cur[tid] = (tid == 0) ? 0 : sc[tid - 1];
    }
    __syncthreads();
    for (int e = tid; e < cnt; e += SORT_T) {
        int2 r = buf[e];
        int pos = atomicAdd(&cur[r.x >> 16], 1);
        sbuf[pos] = r;
    }
    __syncthreads();
    for (int e = tid; e < cnt; e += SORT_T) buf[e] = sbuf[e];
    for (int i = tid; i <= RPB; i += SORT_T) rs[i] = start[i];
}

// ---------------- SpMM: wave per row, 8-deep gather pipelining -------------
template<int F, int VEC, bool OUT_HALF>
__global__ __launch_bounds__(256) void spmm_kernel(const int* __restrict__ rs,
                                                   const int2* __restrict__ bcv,
                                                   const __half* __restrict__ sup,
                                                   const float* __restrict__ bias,
                                                   void* __restrict__ outv, int n) {
    static_assert(F == 64 * VEC, "one wave per row");
    const int wave = threadIdx.x >> 6;
    const int lane = threadIdx.x & 63;
    const int r = blockIdx.x * 4 + wave;
    if (r >= n) return;
    const int b  = r >> 7;
    const int rl = r & (RPB - 1);
    const int* rsb = rs + b * (RPB + 1);
    const int start = rsb[rl];
    const int end   = rsb[rl + 1];
    const int2* eb = bcv + (long)b * BCAP;
    const int f0 = lane * VEC;
    float acc0 = bias[f0];
    float acc1 = (VEC == 2) ? bias[f0 + 1] : 0.f;

    for (int base = start; base < end; base += 64) {
        const int m = min(64, end - base);
        int2 cvl = make_int2(0, 0);
        if (lane < m) cvl = eb[base + lane];
        int j = 0;
        for (; j + 8 <= m; j += 8) {
            int   p[8];
            float v[8];
#pragma unroll
            for (int q = 0; q < 8; ++q) {
                p[q] = __shfl(cvl.x, j + q, 64);
                v[q] = __int_as_float(__shfl(cvl.y, j + q, 64));
            }
            if constexpr (VEC == 2) {
                __half2 s[8];
#pragma unroll
                for (int q = 0; q < 8; ++q)
                    s[q] = *(const __half2*)(sup + (long)(p[q] & 0xFFFF) * F + f0);
#pragma unroll
                for (int q = 0; q < 8; ++q) {
                    float2 gq = __half22float2(s[q]);
                    acc0 += v[q] * gq.x; acc1 += v[q] * gq.y;
                }
            } else {
                float s[8];
#pragma unroll
                for (int q = 0; q < 8; ++q)
                    s[q] = __half2float(sup[(long)(p[q] & 0xFFFF) * F + f0]);
#pragma unroll
                for (int q = 0; q < 8; ++q) acc0 += v[q] * s[q];
            }
        }
        for (; j < m; ++j) {
            const int   p = __shfl(cvl.x, j, 64);
            const float v = __int_as_float(__shfl(cvl.y, j, 64));
            if constexpr (VEC == 2) {
                float2 g = __half22float2(*(const __half2*)(sup + (long)(p & 0xFFFF) * F + f0));
                acc0 += v * g.x; acc1 += v * g.y;
            } else {
                acc0 += v * __half2float(sup[(long)(p & 0xFFFF) * F + f0]);
            }
        }
    }
    if constexpr (OUT_HALF) {
        __half* out = (__half*)outv;
        *(__half2*)(out + (long)r * F + f0) = __floats2half2_rn(acc0, acc1);
    } else {
        float* out = (float*)outv;
        out[(long)r * F + f0] = acc0;
    }
}

extern "C" void kernel_launch(void* const* d_in, const int* in_sizes, int n_in,
                              void* d_out, int out_size, void* d_ws, size_t ws_size,
                              hipStream_t stream) {
    const float* x    = (const float*)d_in[0];
    const int*   row0 = (const int*)d_in[1];
    const int*   col0 = (const int*)d_in[2];
    const float* val0 = (const float*)d_in[3];
    const int*   row1 = (const int*)d_in[4];
    const int*   col1 = (const int*)d_in[5];
    const float* val1 = (const float*)d_in[6];
    const float* W0   = (const float*)d_in[7];
    const float* b0   = (const float*)d_in[8];
    const float* W1   = (const float*)d_in[9];
    const float* b1   = (const float*)d_in[10];
    float* out = (float*)d_out;

    const int M = N_NODES;

    // Workspace layout (8B aligned):
    //   sup0: N*128 fp16 (12.8 MB) -- reused as sup1
    //   h:    N*128 fp16 (12.8 MB)
    //   bcv0, bcv1: NBUCK*BCAP int2 (8 MB each)
    //   rs0, rs1, gfill, wt0, wt1
    __half* sup0 = (__half*)d_ws;
    __half* h    = sup0 + (long)N_NODES * HID_F;
    int2* bcv0   = (int2*)(h + (long)N_NODES * HID_F);
    int2* bcv1   = bcv0 + (long)NBUCK * BCAP;
    int*  rs0    = (int*)(bcv1 + (long)NBUCK * BCAP);
    int*  rs1    = rs0 + NBUCK * (RPB + 1);
    int*  gfill  = rs1 + NBUCK * (RPB + 1);
    __half* wt0  = (__half*)(gfill + 2 * NBUCK + 2);  // [HID_F][IN_F]
    __half* wt1  = wt0 + IN_F * HID_F;                 // [OUT_F][HID_F]
    __half* sup1 = sup0;

    const int SPMM_B = (N_NODES + 3) / 4;

    // ---- Prep (zero gfill + W converts) + sorted-bucket build ----
    prep_kernel<<<(IN_F * HID_F + 255) / 256, 256, 0, stream>>>(W0, W1, wt0, wt1, gfill);
    bin_kernel<<<dim3(BIN_NB, 2), BIN_T, 0, stream>>>(row0, col0, val0, row1, col1, val1,
                                                      gfill, bcv0, bcv1);
    sort_kernel<<<dim3(NBUCK, 2), SORT_T, 0, stream>>>(gfill, bcv0, bcv1, rs0, rs1);

    // ---- Layer 0 ----
    gemm_mfma_kernel<IN_F, HID_F, false, float><<<(M + 63) / 64, 256, 0, stream>>>(x, wt0, sup0, M);
    spmm_kernel<HID_F, 2, true><<<SPMM_B, 256, 0, stream>>>(rs0, bcv0, sup0, b0, h, N_NODES);

    // ---- Layer 1 ----
    gemm_mfma_kernel<HID_F, OUT_F, true, __half><<<(M + 63) / 64, 256, 0, stream>>>(h, wt1, sup1, M);
    spmm_kernel<OUT_F, 1, false><<<SPMM_B, 256, 0, stream>>>(rs1, bcv1, sup1, b1, out, N_NODES);
}

// Round 9
// 187.553 us; speedup vs baseline: 6.6264x; 1.0571x over previous
//
#include <hip/hip_runtime.h>
#include <hip/hip_fp16.h>
#include <type_traits>

#define N_NODES 50000
#define IN_F    128
#define HID_F   128
#define OUT_F   64
#define E_EDGES 800000

#define RPB   128                                  // rows per bucket
#define NBUCK ((N_NODES + RPB - 1) / RPB)          // 391
#define BCAP  2560                                 // capacity (mean 2048, +11 sigma)
#define BIN_T   512
#define BIN_EPT 16
#define BIN_EPB (BIN_T * BIN_EPT)                  // 8192 edges per block
#define BIN_NB  ((E_EDGES + BIN_EPB - 1) / BIN_EPB)  // 98

typedef _Float16 half8 __attribute__((ext_vector_type(8)));
typedef float    floatx4 __attribute__((ext_vector_type(4)));

// ---------------- Prep: zero gfill + convert W0/W1 to fp16 transposed -------
__global__ __launch_bounds__(256) void prep_kernel(const float* __restrict__ W0,
                                                   const float* __restrict__ W1,
                                                   __half* __restrict__ wt0,
                                                   __half* __restrict__ wt1,
                                                   int* __restrict__ gfill) {
    int tid = blockIdx.x * 256 + threadIdx.x;
    if (tid < IN_F * HID_F) {               // wt0[n][k] = W0[k][n], 128x128
        int k = tid >> 7, n = tid & 127;
        wt0[n * IN_F + k] = __float2half(W0[tid]);
    }
    if (tid < HID_F * OUT_F) {              // wt1[n][k] = W1[k][n], 128x64
        int k = tid / OUT_F, n = tid % OUT_F;
        wt1[n * HID_F + k] = __float2half(W1[tid]);
    }
    if (tid < 2 * NBUCK) gfill[tid] = 0;
}

// ---------------- MFMA GEMM: C[M,NF] = act(A)[M,K] @ W[K,NF] ----------------
template<int K, int NF, bool RELU_A, typename AT>
__global__ __launch_bounds__(256) void gemm_mfma_kernel(const AT* __restrict__ A,
                                                        const __half* __restrict__ Wt,
                                                        __half* __restrict__ C, int M) {
    constexpr int KP = K + 8;          // +16B stride: 2-way bank alias (free)
    constexpr int NT = NF / 16;
    __shared__ _Float16 Ws[NF * KP];
    const int tid = threadIdx.x;
    constexpr int CH = NF * K / 8;
    for (int c = tid; c < CH; c += 256) {
        const int n = c / (K / 8), ko = (c % (K / 8)) * 8;
        *(half8*)&Ws[n * KP + ko] = *(const half8*)(Wt + n * K + ko);
    }
    __syncthreads();

    const int wv = tid >> 6, lane = tid & 63;
    const int quad = lane >> 4, l16 = lane & 15;
    const int rowb = blockIdx.x * 64 + wv * 16;
    const int arow = rowb + l16;

    floatx4 acc[NT] = {};
#pragma unroll
    for (int ks = 0; ks < K; ks += 32) {
        half8 af = {};
        if (arow < M) {
            if constexpr (std::is_same<AT, float>::value) {
                const float4* p = (const float4*)(A + (long)arow * K + ks + quad * 8);
                float4 u = p[0], w = p[1];
                af[0] = (_Float16)u.x; af[1] = (_Float16)u.y;
                af[2] = (_Float16)u.z; af[3] = (_Float16)u.w;
                af[4] = (_Float16)w.x; af[5] = (_Float16)w.y;
                af[6] = (_Float16)w.z; af[7] = (_Float16)w.w;
            } else {
                af = *(const half8*)(A + (long)arow * K + ks + quad * 8);
            }
        }
        if (RELU_A) {
            _Float16 z = (_Float16)0;
#pragma unroll
            for (int j = 0; j < 8; ++j) af[j] = af[j] > z ? af[j] : z;
        }
#pragma unroll
        for (int t = 0; t < NT; ++t) {
            half8 bf = *(const half8*)&Ws[(t * 16 + l16) * KP + ks + quad * 8];
            acc[t] = __builtin_amdgcn_mfma_f32_16x16x32_f16(af, bf, acc[t], 0, 0, 0);
        }
    }
#pragma unroll
    for (int t = 0; t < NT; ++t) {
        const int col = t * 16 + l16;
#pragma unroll
        for (int i = 0; i < 4; ++i) {
            const int row = rowb + quad * 4 + i;
            if (row < M) C[(long)row * NF + col] = __float2half(acc[t][i]);
        }
    }
}

// ---------------- Coalesced bucket binning ----------------
__global__ __launch_bounds__(BIN_T) void bin_kernel(
        const int* __restrict__ row0, const int* __restrict__ col0, const float* __restrict__ val0,
        const int* __restrict__ row1, const int* __restrict__ col1, const float* __restrict__ val1,
        int* __restrict__ gfill, int2* __restrict__ bcv0, int2* __restrict__ bcv1) {
    const int g = blockIdx.y;
    const int*   rowi = g ? row1 : row0;
    const int*   coli = g ? col1 : col0;
    const float* vali = g ? val1 : val0;
    int*  gf  = gfill + g * NBUCK;
    int2* bcv = g ? bcv1 : bcv0;

    __shared__ int lhist[NBUCK];
    __shared__ int lbase[NBUCK];
    const int tid = threadIdx.x;
    for (int i = tid; i < NBUCK; i += BIN_T) lhist[i] = 0;
    __syncthreads();

    int rnk[BIN_EPT], bkt[BIN_EPT], cl[BIN_EPT], rw[BIN_EPT];
    float vl[BIN_EPT];
    const int e0 = blockIdx.x * BIN_EPB;
#pragma unroll
    for (int i = 0; i < BIN_EPT; ++i) {
        const int e = e0 + i * BIN_T + tid;
        bkt[i] = -1;
        if (e < E_EDGES) {
            const int r = rowi[e];
            rw[i] = r; cl[i] = coli[e]; vl[i] = vali[e];
            const int b = r / RPB;
            bkt[i] = b;
            rnk[i] = atomicAdd(&lhist[b], 1);
        }
    }
    __syncthreads();
    for (int i = tid; i < NBUCK; i += BIN_T) {
        const int c = lhist[i];
        lbase[i] = c ? atomicAdd(&gf[i], c) : 0;
    }
    __syncthreads();
#pragma unroll
    for (int i = 0; i < BIN_EPT; ++i) {
        if (bkt[i] >= 0) {
            const int pos = lbase[bkt[i]] + rnk[i];
            if (pos < BCAP)
                bcv[(long)bkt[i] * BCAP + pos] =
                    make_int2(((rw[i] & (RPB - 1)) << 16) | cl[i], __float_as_int(vl[i]));
        }
    }
}

// ---------------- Per-bucket counting sort (single global read) ------------
#define SORT_T 512
#define SORT_EPT (BCAP / SORT_T)    // 5
__global__ __launch_bounds__(SORT_T) void sort_kernel(const int* __restrict__ gfill,
                                                      int2* __restrict__ bcv0,
                                                      int2* __restrict__ bcv1,
                                                      int* __restrict__ rs0,
                                                      int* __restrict__ rs1) {
    const int g = blockIdx.y;
    const int b = blockIdx.x;
    int2* buf = (g ? bcv1 : bcv0) + (long)b * BCAP;
    int*  rs  = (g ? rs1 : rs0) + b * (RPB + 1);

    __shared__ int2 sbuf[BCAP];       // 20 KB
    __shared__ int  cur[RPB];
    __shared__ int  sc[RPB];
    __shared__ int  start[RPB + 1];

    const int tid = threadIdx.x;
    int cnt = gfill[g * NBUCK + b];
    if (cnt > BCAP) cnt = BCAP;

    // single coalesced read into registers
    int2 ed[SORT_EPT];
#pragma unroll
    for (int k = 0; k < SORT_EPT; ++k) {
        const int e = tid + k * SORT_T;
        if (e < cnt) ed[k] = buf[e];
    }

    if (tid < RPB) cur[tid] = 0;
    __syncthreads();
#pragma unroll
    for (int k = 0; k < SORT_EPT; ++k)
        if (tid + k * SORT_T < cnt) atomicAdd(&cur[ed[k].x >> 16], 1);
    __syncthreads();
    if (tid < RPB) sc[tid] = cur[tid];
    __syncthreads();
    for (int off = 1; off < RPB; off <<= 1) {
        int v = 0;
        if (tid < RPB && tid >= off) v = sc[tid - off];
        __syncthreads();
        if (tid < RPB) sc[tid] += v;
        __syncthreads();
    }
    if (tid < RPB) {
        start[tid + 1] = sc[tid];
        if (tid == 0) start[0] = 0;
        cur[tid] = (tid == 0) ? 0 : sc[tid - 1];
    }
    __syncthreads();
#pragma unroll
    for (int k = 0; k < SORT_EPT; ++k) {
        if (tid + k * SORT_T < cnt) {
            int pos = atomicAdd(&cur[ed[k].x >> 16], 1);
            sbuf[pos] = ed[k];
        }
    }
    __syncthreads();
#pragma unroll
    for (int k = 0; k < SORT_EPT; ++k) {
        const int e = tid + k * SORT_T;
        if (e < cnt) buf[e] = sbuf[e];
    }
    for (int i = tid; i <= RPB; i += SORT_T) rs[i] = start[i];
}

// ---------------- SpMM: wave per row, fully pipelined padded batches -------
// Lanes >= m hold (0,0) records, so every 8-batch runs full-width with v=0
// padding (gathers row 0 harmlessly) -- zero serial dependent gathers.
template<int F, int VEC, bool OUT_HALF>
__global__ __launch_bounds__(256) void spmm_kernel(const int* __restrict__ rs,
                                                   const int2* __restrict__ bcv,
                                                   const __half* __restrict__ sup,
                                                   const float* __restrict__ bias,
                                                   void* __restrict__ outv, int n) {
    static_assert(F == 64 * VEC, "one wave per row");
    const int wave = threadIdx.x >> 6;
    const int lane = threadIdx.x & 63;
    const int r = blockIdx.x * 4 + wave;
    if (r >= n) return;
    const int b  = r >> 7;
    const int rl = r & (RPB - 1);
    const int* rsb = rs + b * (RPB + 1);
    const int start = rsb[rl];
    const int end   = rsb[rl + 1];
    const int2* eb = bcv + (long)b * BCAP;
    const int f0 = lane * VEC;
    float acc0 = bias[f0];
    float acc1 = (VEC == 2) ? bias[f0 + 1] : 0.f;

    for (int base = start; base < end; base += 64) {
        const int m = min(64, end - base);
        int2 cvl = make_int2(0, 0);
        if (lane < m) cvl = eb[base + lane];
        for (int j = 0; j < m; j += 8) {
            int   p[8];
            float v[8];
#pragma unroll
            for (int q = 0; q < 8; ++q) {
                p[q] = __shfl(cvl.x, j + q, 64);      // lanes >= m give (0,0)
                v[q] = __int_as_float(__shfl(cvl.y, j + q, 64));
            }
            if constexpr (VEC == 2) {
                __half2 s[8];
#pragma unroll
                for (int q = 0; q < 8; ++q)
                    s[q] = *(const __half2*)(sup + (long)(p[q] & 0xFFFF) * F + f0);
#pragma unroll
                for (int q = 0; q < 8; ++q) {
                    float2 gq = __half22float2(s[q]);
                    acc0 += v[q] * gq.x; acc1 += v[q] * gq.y;
                }
            } else {
                float s[8];
#pragma unroll
                for (int q = 0; q < 8; ++q)
                    s[q] = __half2float(sup[(long)(p[q] & 0xFFFF) * F + f0]);
#pragma unroll
                for (int q = 0; q < 8; ++q) acc0 += v[q] * s[q];
            }
        }
    }
    if constexpr (OUT_HALF) {
        __half* out = (__half*)outv;
        *(__half2*)(out + (long)r * F + f0) = __floats2half2_rn(acc0, acc1);
    } else {
        float* out = (float*)outv;
        out[(long)r * F + f0] = acc0;
    }
}

extern "C" void kernel_launch(void* const* d_in, const int* in_sizes, int n_in,
                              void* d_out, int out_size, void* d_ws, size_t ws_size,
                              hipStream_t stream) {
    const float* x    = (const float*)d_in[0];
    const int*   row0 = (const int*)d_in[1];
    const int*   col0 = (const int*)d_in[2];
    const float* val0 = (const float*)d_in[3];
    const int*   row1 = (const int*)d_in[4];
    const int*   col1 = (const int*)d_in[5];
    const float* val1 = (const float*)d_in[6];
    const float* W0   = (const float*)d_in[7];
    const float* b0   = (const float*)d_in[8];
    const float* W1   = (const float*)d_in[9];
    const float* b1   = (const float*)d_in[10];
    float* out = (float*)d_out;

    const int M = N_NODES;

    __half* sup0 = (__half*)d_ws;
    __half* h    = sup0 + (long)N_NODES * HID_F;
    int2* bcv0   = (int2*)(h + (long)N_NODES * HID_F);
    int2* bcv1   = bcv0 + (long)NBUCK * BCAP;
    int*  rs0    = (int*)(bcv1 + (long)NBUCK * BCAP);
    int*  rs1    = rs0 + NBUCK * (RPB + 1);
    int*  gfill  = rs1 + NBUCK * (RPB + 1);
    __half* wt0  = (__half*)(gfill + 2 * NBUCK + 2);  // [HID_F][IN_F]
    __half* wt1  = wt0 + IN_F * HID_F;                 // [OUT_F][HID_F]
    __half* sup1 = sup0;

    const int SPMM_B = (N_NODES + 3) / 4;

    // ---- Prep (zero gfill + W converts) + sorted-bucket build ----
    prep_kernel<<<(IN_F * HID_F + 255) / 256, 256, 0, stream>>>(W0, W1, wt0, wt1, gfill);
    bin_kernel<<<dim3(BIN_NB, 2), BIN_T, 0, stream>>>(row0, col0, val0, row1, col1, val1,
                                                      gfill, bcv0, bcv1);
    sort_kernel<<<dim3(NBUCK, 2), SORT_T, 0, stream>>>(gfill, bcv0, bcv1, rs0, rs1);

    // ---- Layer 0 ----
    gemm_mfma_kernel<IN_F, HID_F, false, float><<<(M + 63) / 64, 256, 0, stream>>>(x, wt0, sup0, M);
    spmm_kernel<HID_F, 2, true><<<SPMM_B, 256, 0, stream>>>(rs0, bcv0, sup0, b0, h, N_NODES);

    // ---- Layer 1 ----
    gemm_mfma_kernel<HID_F, OUT_F, true, __half><<<(M + 63) / 64, 256, 0, stream>>>(h, wt1, sup1, M);
    spmm_kernel<OUT_F, 1, false><<<SPMM_B, 256, 0, stream>>>(rs1, bcv1, sup1, b1, out, N_NODES);
}